// Round 1
// baseline (360.735 us; speedup 1.0000x reference)
//
#include <hip/hip_runtime.h>

#define BATCH 8
#define MPTS 500000
#define X 128
#define X3 (X * X * X)

// One thread per point: random atomic scatter-add into per-batch 128^3 grid.
__global__ void scatter_k(const int* __restrict__ idx,
                          const float* __restrict__ val,
                          float* __restrict__ grid) {
    long long t = (long long)blockIdx.x * blockDim.x + threadIdx.x;
    if (t >= (long long)BATCH * MPTS) return;
    int b = (int)(t / MPTS);
    const int* p = idx + t * 3;
    int i = p[0], j = p[1], k = p[2];
    atomicAdd(grid + (size_t)b * X3 + ((size_t)i << 14) + (j << 7) + k,
              val[t]);
}

// Stencil + reduction: per-voxel forward diffs along the 3 axes,
// accumulate |d| and d^2, block-reduce, one atomic per block.
__global__ void tv_k(const float* __restrict__ grid, float* __restrict__ out) {
    int b = blockIdx.y;
    const float* g = grid + (size_t)b * X3;
    float tv = 0.f, mse = 0.f;
    for (int v = blockIdx.x * blockDim.x + threadIdx.x; v < X3;
         v += blockDim.x * gridDim.x) {
        float c = g[v];
        int k = v & (X - 1);
        int j = (v >> 7) & (X - 1);
        int i = v >> 14;
        if (i < X - 1) { float d = g[v + X * X] - c; tv += fabsf(d); mse += d * d; }
        if (j < X - 1) { float d = g[v + X]     - c; tv += fabsf(d); mse += d * d; }
        if (k < X - 1) { float d = g[v + 1]     - c; tv += fabsf(d); mse += d * d; }
    }
    // wave-64 shuffle reduction
    for (int off = 32; off > 0; off >>= 1) {
        tv  += __shfl_down(tv, off, 64);
        mse += __shfl_down(mse, off, 64);
    }
    __shared__ float s_tv[4], s_mse[4];  // 256 threads = 4 waves
    int wave = threadIdx.x >> 6;
    int lane = threadIdx.x & 63;
    if (lane == 0) { s_tv[wave] = tv; s_mse[wave] = mse; }
    __syncthreads();
    if (threadIdx.x == 0) {
        float tsum = s_tv[0] + s_tv[1] + s_tv[2] + s_tv[3];
        float msum = s_mse[0] + s_mse[1] + s_mse[2] + s_mse[3];
        atomicAdd(&out[b],         tsum * (1.f / (float)X3));
        atomicAdd(&out[BATCH + b], msum * (1.f / 32512.f));  // 2*X*X - 2*X
    }
}

extern "C" void kernel_launch(void* const* d_in, const int* in_sizes, int n_in,
                              void* d_out, int out_size, void* d_ws, size_t ws_size,
                              hipStream_t stream) {
    const int*   indices = (const int*)d_in[0];   // (B, M, 3) int32
    const float* values  = (const float*)d_in[1]; // (B, M) float32
    float*       out     = (float*)d_out;         // (2, B) float32
    float*       grid    = (float*)d_ws;          // B * X^3 floats = 64 MiB

    size_t grid_bytes = (size_t)BATCH * X3 * sizeof(float);
    hipMemsetAsync(grid, 0, grid_bytes, stream);
    hipMemsetAsync(out, 0, 2 * BATCH * sizeof(float), stream);

    int total = BATCH * MPTS;
    scatter_k<<<(total + 255) / 256, 256, 0, stream>>>(indices, values, grid);

    dim3 g2(256, BATCH);
    tv_k<<<g2, 256, 0, stream>>>(grid, out);
}